// Round 2
// baseline (6801.944 us; speedup 1.0000x reference)
//
#include <hip/hip_runtime.h>
#include <hip/hip_bf16.h>

// SliceLSTM persistent kernel for gfx950, round 6 + barrier watchdog.
// 128 blocks x 256 thr: 4 batch quarters x 32 j-tiles; wave = gate.
// Weight hi-planes in LDS, lo-planes in VGPRs. Cross-block data via sc1
// write-through stores + relaxed agent atomic loads (L3), NO cache inv.
// Flag-based barriers (no RMW contention): barrier1 = 32-wide (acts,
// ping-pong buffered), barrier2 = 8-wide slice group (h exchange).
// hidden_seq stores deferred one step; x prefetched during phase 2.
// Watchdog: poll loops break after ~16M spins (~0.5s) so a residency
// deadlock surfaces as a fast wrong-answer instead of a container kill.

typedef unsigned short u16;
typedef unsigned long long u64;
typedef __attribute__((ext_vector_type(8))) short short8;
typedef __attribute__((ext_vector_type(4))) float floatx4;

#define NT 256
#define NBLK 128
#define TSTEPS 512

// ---- workspace layout (bytes) ----
#define WS_FLAG1 0                        // 4 quarters x 32 u32 (256 B stride)
#define WS_FLAG2 1024                     // 16 groups x 8 u32 (64 B stride)
#define WS_H_HI 2048                      // 64 b x 512 j u16
#define WS_H_LO (WS_H_HI + 65536)
#define WS_ZERO_BYTES (WS_H_LO + 65536)   // zeroed every call
#define WS_ACT_HI (WS_ZERO_BYTES)         // 2 planes x [4g][64b][512k] u16
#define WS_ACT_LO (WS_ACT_HI + 2 * 262144)
#define ACT_PLANE 131072                  // elements per plane

__device__ __forceinline__ float b2f(u16 u) {
  unsigned v = ((unsigned)u) << 16;
  float f;
  __builtin_memcpy(&f, &v, 4);
  return f;
}
__device__ __forceinline__ u16 f2b(float f) {
  __hip_bfloat16 h = __float2bfloat16(f);  // RNE
  u16 u;
  __builtin_memcpy(&u, &h, 2);
  return u;
}
__device__ __forceinline__ float sigf(float x) { return 1.0f / (1.0f + __expf(-x)); }
__device__ __forceinline__ float tanhf_fast(float x) { return 2.0f * sigf(2.0f * x) - 1.0f; }
__device__ __forceinline__ short8 ld8(const u16* p) { return *(const short8*)p; }

// coherent 16B fragment load (sc1, straight from L3; relaxed -> batchable)
__device__ __forceinline__ short8 lda_frag(const u16* p) {
  union {
    u64 q[2];
    short8 s;
  } u;
  u.q[0] = __hip_atomic_load((const u64*)p, __ATOMIC_RELAXED, __HIP_MEMORY_SCOPE_AGENT);
  u.q[1] = __hip_atomic_load((const u64*)(p + 4), __ATOMIC_RELAXED, __HIP_MEMORY_SCOPE_AGENT);
  return u.s;
}
__device__ __forceinline__ void sta16(u16* p, u16 v) {
  __hip_atomic_store(p, v, __ATOMIC_RELAXED, __HIP_MEMORY_SCOPE_AGENT);
}

__device__ __forceinline__ void split8v(float4 a, float4 b, short8& hi, short8& lo) {
  float v[8] = {a.x, a.y, a.z, a.w, b.x, b.y, b.z, b.w};
#pragma unroll
  for (int i = 0; i < 8; ++i) {
    u16 h = f2b(v[i]);
    hi[i] = (short)h;
    lo[i] = (short)f2b(v[i] - b2f(h));
  }
}

// Flag barrier: arrival = sc1 store to own dword (no RMW contention);
// wave 0 polls all flags in one vector load + ballot. No cache maintenance.
// Bounded spin: breaks after ~16M polls so a deadlock becomes a fast
// wrong-answer (diagnostic) instead of a hang. Normal barriers complete in
// O(100) polls, so this never triggers when the grid is co-resident.
__device__ __forceinline__ void barrier_flags(unsigned* flags, int nmask, int myidx,
                                              unsigned target) {
  asm volatile("s_waitcnt vmcnt(0)" ::: "memory");
  __syncthreads();
  const int tid = threadIdx.x;
  if (tid == 0)
    __hip_atomic_store(&flags[myidx], target, __ATOMIC_RELAXED, __HIP_MEMORY_SCOPE_AGENT);
  if (tid < 64) {
    const int fi = tid & nmask;
    int spins = 0;
    for (;;) {
      const unsigned v =
          __hip_atomic_load(&flags[fi], __ATOMIC_RELAXED, __HIP_MEMORY_SCOPE_AGENT);
      if (__ballot(v >= target) == ~0ULL) break;
      if (++spins > (1 << 24)) break;  // watchdog (see header comment)
      __builtin_amdgcn_s_sleep(1);
    }
  }
  __syncthreads();
}

__global__ void __launch_bounds__(NT) init_ws_kernel(unsigned* w, int n) {
  int i = blockIdx.x * blockDim.x + threadIdx.x;
  const int st = gridDim.x * blockDim.x;
  for (; i < n; i += st) w[i] = 0u;
}

__global__ void __launch_bounds__(NT, 1) slicelstm_kernel(
    const float* __restrict__ x, const float* __restrict__ Ws,
    const float* __restrict__ Us, const float* __restrict__ biases,
    const float* __restrict__ Wc, const float* __restrict__ bcg,
    float* __restrict__ out, u16* __restrict__ act_hi, u16* __restrict__ act_lo,
    u16* __restrict__ h_hi, u16* __restrict__ h_lo, unsigned* __restrict__ flagbase) {
  __shared__ __align__(16) u16 W1H[64 * 200];  // [row=g*16+jj][k 0..191] +8 pad
  __shared__ __align__(16) u16 W2H[64 * 520];  // [row=g*16+jj][k 0..511] +8 pad
  __shared__ float gx[4][16][17];              // gate exchange, +1 pad

  const int tid = threadIdx.x;
  const int blk = blockIdx.x;
  const int q = blk & 3;    // batch quarter
  const int jt = blk >> 2;  // j-tile 0..31
  const int j0 = jt * 16;
  const int s = j0 >> 7;    // slice 0..3
  const int jbase = j0 & 127;
  unsigned* flags1 = flagbase + q * 64;                        // 32 flags
  unsigned* flags2 = flagbase + 256 + (q * 4 + s) * 16;        // 8 flags

  // ---- one-time: split f32 weights, hi-planes -> LDS ----
  for (int i = tid; i < 64 * 192; i += NT) {
    const int r = i / 192, k = i % 192;
    const int col = (r >> 4) * 128 + jbase + (r & 15);
    const float w = (k < 64) ? Ws[(size_t)(s * 64 + k) * 512 + col]
                             : Us[(size_t)(s * 128 + (k - 64)) * 512 + col];
    W1H[r * 200 + k] = f2b(w);
  }
  for (int i = tid; i < 64 * 512; i += NT) {
    const int r = i >> 9, k = i & 511;
    const int col = (r >> 4) * 512 + j0 + (r & 15);
    W2H[r * 520 + k] = f2b(Wc[(size_t)k * 2048 + col]);
  }

  const int lane = tid & 63;
  const int g = tid >> 6;   // wave = gate
  const int lm = lane & 15;
  const int lq = lane >> 4;
  const int ko = lq * 8;

  // ---- one-time: lo-plane fragments -> VGPRs ----
  short8 w1l[6], w2l[16];
#pragma unroll
  for (int kt = 0; kt < 6; ++kt) {
    const int col = (g << 7) + jbase + lm;
#pragma unroll
    for (int e = 0; e < 8; ++e) {
      const int k = kt * 32 + ko + e;
      const float w = (k < 64) ? Ws[(size_t)(s * 64 + k) * 512 + col]
                               : Us[(size_t)(s * 128 + (k - 64)) * 512 + col];
      w1l[kt][e] = (short)f2b(w - b2f(f2b(w)));
    }
  }
#pragma unroll
  for (int kt = 0; kt < 16; ++kt) {
    const int col = (g << 9) + j0 + lm;
#pragma unroll
    for (int e = 0; e < 8; ++e) {
      const float w = Wc[(size_t)(kt * 32 + ko + e) * 2048 + col];
      w2l[kt][e] = (short)f2b(w - b2f(f2b(w)));
    }
  }
  const float biasv = biases[s * 512 + (g << 7) + jbase + lm];
  const float bcv = bcg[(g << 9) + j0 + lm];
  __syncthreads();

  const u16* w1r = &W1H[((g << 4) + lm) * 200];
  const u16* w2r = &W2H[((g << 4) + lm) * 520];
  const int brow = q * 16 + lm;
  const float* xrow = x + (size_t)brow * (512 * 256) + s * 64;
  const int hbase = brow * 512 + s * 128;
  const int arow_off = ((g << 6) + brow) * 512;

  // phase-3 mapping
  const int p3b = tid >> 4, p3j = tid & 15;
  const int p3ci = (q * 16 + p3b) * 512 + j0 + p3j;
  const size_t obase = (size_t)(q * 16 + p3b) * TSTEPS * 512 + j0 + p3j;
  float creg = 0.f, hprev = 0.f;

  // x prefetch registers for t=0
  float4 xa0, xb0, xa1, xb1;
  {
    const float* xp = xrow;
    xa0 = *(const float4*)(xp + ko);
    xb0 = *(const float4*)(xp + ko + 4);
    xa1 = *(const float4*)(xp + 32 + ko);
    xb1 = *(const float4*)(xp + 32 + ko + 4);
  }

  for (int t = 0; t < TSTEPS; ++t) {
    // ---- phase 0: deferred hidden_seq store; build A-fragments ----
    if (t > 0) __builtin_nontemporal_store(hprev, &out[obase + (size_t)(t - 1) * 512]);
    short8 xh[2], xl[2], hh[4], hl[4];
    split8v(xa0, xb0, xh[0], xl[0]);
    split8v(xa1, xb1, xh[1], xl[1]);
#pragma unroll
    for (int kt = 0; kt < 4; ++kt) {
      hh[kt] = lda_frag(&h_hi[hbase + kt * 32 + ko]);
      hl[kt] = lda_frag(&h_lo[hbase + kt * 32 + ko]);
    }

    // ---- phase 1: stage-1 gate (this wave's) -> act bufs (sc1) ----
    {
      floatx4 accA = {0.f, 0.f, 0.f, 0.f}, accB = {0.f, 0.f, 0.f, 0.f};
      floatx4 accC = {0.f, 0.f, 0.f, 0.f};
#pragma unroll
      for (int kt = 0; kt < 2; ++kt) {
        const short8 bh = ld8(w1r + kt * 32 + ko);
        accA = __builtin_amdgcn_mfma_f32_16x16x32_bf16(xh[kt], bh, accA, 0, 0, 0);
        accB = __builtin_amdgcn_mfma_f32_16x16x32_bf16(xl[kt], bh, accB, 0, 0, 0);
        accC = __builtin_amdgcn_mfma_f32_16x16x32_bf16(xh[kt], w1l[kt], accC, 0, 0, 0);
      }
#pragma unroll
      for (int kt = 0; kt < 4; ++kt) {
        const short8 bh = ld8(w1r + 64 + kt * 32 + ko);
        accA = __builtin_amdgcn_mfma_f32_16x16x32_bf16(hh[kt], bh, accA, 0, 0, 0);
        accB = __builtin_amdgcn_mfma_f32_16x16x32_bf16(hl[kt], bh, accB, 0, 0, 0);
        accC = __builtin_amdgcn_mfma_f32_16x16x32_bf16(hh[kt], w1l[2 + kt], accC, 0, 0, 0);
      }
      const int pp = (t & 1) * ACT_PLANE;
#pragma unroll
      for (int r = 0; r < 4; ++r) {
        const int b = q * 16 + lq * 4 + r;
        const float pre = accA[r] + accB[r] + accC[r] + biasv;
        const float a = (g == 2) ? tanhf_fast(pre) : sigf(pre);
        const u16 ah = f2b(a);
        const int o = pp + ((g << 6) + b) * 512 + j0 + lm;
        sta16(&act_hi[o], ah);
        sta16(&act_lo[o], f2b(a - b2f(ah)));
      }
    }
    barrier_flags(flags1, 31, jt, (unsigned)(t + 1));

    // ---- phase 2: prefetch x(t+1); connector GEMM (acts via L3) ----
    {
      const float* xp = xrow + (t < TSTEPS - 1 ? (t + 1) : t) * 256;
      xa0 = *(const float4*)(xp + ko);
      xb0 = *(const float4*)(xp + ko + 4);
      xa1 = *(const float4*)(xp + 32 + ko);
      xb1 = *(const float4*)(xp + 32 + ko + 4);
    }
    floatx4 a2a = {0.f, 0.f, 0.f, 0.f}, a2b = {0.f, 0.f, 0.f, 0.f};
    floatx4 a2c = {0.f, 0.f, 0.f, 0.f}, a2d = {0.f, 0.f, 0.f, 0.f};
    {
      const u16* ah = act_hi + (t & 1) * ACT_PLANE + arow_off;
      const u16* al = act_lo + (t & 1) * ACT_PLANE + arow_off;
#pragma unroll
      for (int kt = 0; kt < 16; kt += 2) {
        const int kb0 = kt * 32 + ko, kb1 = (kt + 1) * 32 + ko;
        const short8 Ah0 = lda_frag(ah + kb0), Al0 = lda_frag(al + kb0);
        const short8 Ah1 = lda_frag(ah + kb1), Al1 = lda_frag(al + kb1);
        const short8 Bh0 = ld8(w2r + kb0), Bh1 = ld8(w2r + kb1);
        a2a = __builtin_amdgcn_mfma_f32_16x16x32_bf16(Ah0, Bh0, a2a, 0, 0, 0);
        a2b = __builtin_amdgcn_mfma_f32_16x16x32_bf16(Al0, Bh0, a2b, 0, 0, 0);
        a2c = __builtin_amdgcn_mfma_f32_16x16x32_bf16(Ah0, w2l[kt], a2c, 0, 0, 0);
        a2d = __builtin_amdgcn_mfma_f32_16x16x32_bf16(Ah1, Bh1, a2d, 0, 0, 0);
        a2a = __builtin_amdgcn_mfma_f32_16x16x32_bf16(Al1, Bh1, a2a, 0, 0, 0);
        a2b = __builtin_amdgcn_mfma_f32_16x16x32_bf16(Ah1, w2l[kt + 1], a2b, 0, 0, 0);
      }
    }
#pragma unroll
    for (int r = 0; r < 4; ++r)
      gx[g][lq * 4 + r][lm] = (a2a[r] + a2b[r]) + (a2c[r] + a2d[r]) + bcv;
    __syncthreads();

    // ---- phase 3: elementwise update; h stores (sc1) ----
    {
      const float it = sigf(gx[0][p3b][p3j]);
      const float ft = sigf(gx[1][p3b][p3j]);
      const float gt = tanhf_fast(gx[2][p3b][p3j]);
      const float ot = sigf(gx[3][p3b][p3j]);
      const float cn = ft * creg + it * gt;
      creg = cn;
      const float h = ot * tanhf_fast(cn);
      hprev = h;
      if (t < TSTEPS - 1) {
        const u16 hh2 = f2b(h);
        sta16(&h_hi[p3ci], hh2);
        sta16(&h_lo[p3ci], f2b(h - b2f(hh2)));
      } else {
        __builtin_nontemporal_store(h, &out[obase + (size_t)t * 512]);
        __builtin_nontemporal_store(h, &out[16777216 + p3ci]);
        __builtin_nontemporal_store(cn, &out[16777216 + 32768 + p3ci]);
      }
    }
    if (t < TSTEPS - 1) barrier_flags(flags2, 7, jt & 7, (unsigned)(t + 1));
  }
}

extern "C" void kernel_launch(void* const* d_in, const int* in_sizes, int n_in,
                              void* d_out, int out_size, void* d_ws, size_t ws_size,
                              hipStream_t stream) {
  const float* x = (const float*)d_in[0];
  const float* Ws = (const float*)d_in[1];
  const float* Us = (const float*)d_in[2];
  const float* biases = (const float*)d_in[3];
  const float* Wc = (const float*)d_in[4];
  const float* bc = (const float*)d_in[5];

  char* ws = (char*)d_ws;
  unsigned* flagbase = (unsigned*)(ws + WS_FLAG1);
  u16* h_hi = (u16*)(ws + WS_H_HI);
  u16* h_lo = (u16*)(ws + WS_H_LO);
  u16* act_hi = (u16*)(ws + WS_ACT_HI);
  u16* act_lo = (u16*)(ws + WS_ACT_LO);

  hipLaunchKernelGGL(init_ws_kernel, dim3(64), dim3(NT), 0, stream, (unsigned*)ws,
                     WS_ZERO_BYTES / 4);
  hipLaunchKernelGGL(slicelstm_kernel, dim3(NBLK), dim3(NT), 0, stream, x, Ws, Us,
                     biases, Wc, bc, (float*)d_out, act_hi, act_lo, h_hi, h_lo, flagbase);
}

// Round 5
// 4899.030 us; speedup vs baseline: 1.3884x; 1.3884x over previous
//
#include <hip/hip_runtime.h>
#include <hip/hip_bf16.h>

// SliceLSTM persistent kernel for gfx950, round 9.
// REVERTED to the verified round-6 architecture: 128 blocks x 256 thr
// (4 batch quarters x 32 j-tiles, wave = gate), cross-block exchange via
// agent-scope (sc1/L3) relaxed atomics, flag barriers (32-wide acts,
// 8-wide h-group), watchdog-bounded polls.
// Round-9 deltas (sync semantics untouched):
//  * act exchange is single bf16 plane (act_lo dropped): halves act
//    stores/loads, phase-2 MFMAs 48->32. Numerics margin ~3x.
//  * barrier2 split into arrive2 (end of step) + wait2 (next step, after
//    the h-independent x-part MFMAs) -- overlaps flag visibility.
//  * hidden_seq store + x prefetch issued after the act-load drain, so
//    their latency drains at arrive2 instead of the critical path.

typedef unsigned short u16;
typedef unsigned long long u64;
typedef __attribute__((ext_vector_type(8))) short short8;
typedef __attribute__((ext_vector_type(4))) float floatx4;

#define NT 256
#define NBLK 128
#define TSTEPS 512

// ---- workspace layout (bytes) ----
#define WS_FLAG1 0                        // 4 quarters x 32 u32 (256 B stride)
#define WS_FLAG2 1024                     // 16 groups x 8 u32 (64 B stride)
#define WS_H_HI 2048                      // 64 b x 512 j u16
#define WS_H_LO (WS_H_HI + 65536)
#define WS_ZERO_BYTES (WS_H_LO + 65536)   // zeroed every call
#define WS_ACT_HI (WS_ZERO_BYTES)         // 2 planes x [4g][64b][512k] u16
#define ACT_PLANE 131072                  // elements per plane

__device__ __forceinline__ float b2f(u16 u) {
  unsigned v = ((unsigned)u) << 16;
  float f;
  __builtin_memcpy(&f, &v, 4);
  return f;
}
__device__ __forceinline__ u16 f2b(float f) {
  __hip_bfloat16 h = __float2bfloat16(f);  // RNE
  u16 u;
  __builtin_memcpy(&u, &h, 2);
  return u;
}
__device__ __forceinline__ float sigf(float x) { return 1.0f / (1.0f + __expf(-x)); }
__device__ __forceinline__ float tanhf_fast(float x) { return 2.0f * sigf(2.0f * x) - 1.0f; }
__device__ __forceinline__ short8 ld8(const u16* p) { return *(const short8*)p; }

// coherent 16B fragment load (sc1, straight from L3; relaxed -> batchable)
__device__ __forceinline__ short8 lda_frag(const u16* p) {
  union {
    u64 q[2];
    short8 s;
  } u;
  u.q[0] = __hip_atomic_load((const u64*)p, __ATOMIC_RELAXED, __HIP_MEMORY_SCOPE_AGENT);
  u.q[1] = __hip_atomic_load((const u64*)(p + 4), __ATOMIC_RELAXED, __HIP_MEMORY_SCOPE_AGENT);
  return u.s;
}
__device__ __forceinline__ void sta16(u16* p, u16 v) {
  __hip_atomic_store(p, v, __ATOMIC_RELAXED, __HIP_MEMORY_SCOPE_AGENT);
}

__device__ __forceinline__ void split8v(float4 a, float4 b, short8& hi, short8& lo) {
  float v[8] = {a.x, a.y, a.z, a.w, b.x, b.y, b.z, b.w};
#pragma unroll
  for (int i = 0; i < 8; ++i) {
    u16 h = f2b(v[i]);
    hi[i] = (short)h;
    lo[i] = (short)f2b(v[i] - b2f(h));
  }
}

// Wait-only half of a flag barrier: wave 0 polls, all threads gated after.
// Bounded spin: a deadlock becomes a fast wrong-answer, not a hang.
__device__ __forceinline__ void wait_flags(unsigned* flags, int nmask, unsigned target) {
  if (threadIdx.x < 64) {
    const int fi = threadIdx.x & nmask;
    int spins = 0;
    for (;;) {
      const unsigned v =
          __hip_atomic_load(&flags[fi], __ATOMIC_RELAXED, __HIP_MEMORY_SCOPE_AGENT);
      if (__ballot(v >= target) == ~0ULL) break;
      if (++spins > (1 << 24)) break;  // watchdog
      __builtin_amdgcn_s_sleep(1);
    }
  }
  __syncthreads();
}
// Arrive-only half: drain this block's stores, then publish the flag.
__device__ __forceinline__ void arrive_flags(unsigned* flags, int myidx, unsigned target) {
  asm volatile("s_waitcnt vmcnt(0)" ::: "memory");
  __syncthreads();
  if (threadIdx.x == 0)
    __hip_atomic_store(&flags[myidx], target, __ATOMIC_RELAXED, __HIP_MEMORY_SCOPE_AGENT);
}
// Combined barrier (arrival + wait), as verified in round 6.
__device__ __forceinline__ void barrier_flags(unsigned* flags, int nmask, int myidx,
                                              unsigned target) {
  arrive_flags(flags, myidx, target);
  wait_flags(flags, nmask, target);
}

__global__ void __launch_bounds__(NT) init_ws_kernel(unsigned* w, int n) {
  int i = blockIdx.x * blockDim.x + threadIdx.x;
  const int st = gridDim.x * blockDim.x;
  for (; i < n; i += st) w[i] = 0u;
}

__global__ void __launch_bounds__(NT, 1) slicelstm_kernel(
    const float* __restrict__ x, const float* __restrict__ Ws,
    const float* __restrict__ Us, const float* __restrict__ biases,
    const float* __restrict__ Wc, const float* __restrict__ bcg,
    float* __restrict__ out, u16* __restrict__ act_hi, u16* __restrict__ h_hi,
    u16* __restrict__ h_lo, unsigned* __restrict__ flagbase) {
  __shared__ __align__(16) u16 W1H[64 * 200];  // [row=g*16+jj][k 0..191] +8 pad
  __shared__ __align__(16) u16 W2H[64 * 520];  // [row=g*16+jj][k 0..511] +8 pad
  __shared__ float gx[4][16][17];              // gate exchange, +1 pad

  const int tid = threadIdx.x;
  const int blk = blockIdx.x;
  const int q = blk & 3;    // batch quarter
  const int jt = blk >> 2;  // j-tile 0..31
  const int j0 = jt * 16;
  const int s = j0 >> 7;    // slice 0..3
  const int jbase = j0 & 127;
  unsigned* flags1 = flagbase + q * 64;                        // 32 flags
  unsigned* flags2 = flagbase + 256 + (q * 4 + s) * 16;        // 8 flags

  // ---- one-time: split f32 weights, hi-planes -> LDS ----
  for (int i = tid; i < 64 * 192; i += NT) {
    const int r = i / 192, k = i % 192;
    const int col = (r >> 4) * 128 + jbase + (r & 15);
    const float w = (k < 64) ? Ws[(size_t)(s * 64 + k) * 512 + col]
                             : Us[(size_t)(s * 128 + (k - 64)) * 512 + col];
    W1H[r * 200 + k] = f2b(w);
  }
  for (int i = tid; i < 64 * 512; i += NT) {
    const int r = i >> 9, k = i & 511;
    const int col = (r >> 4) * 512 + j0 + (r & 15);
    W2H[r * 520 + k] = f2b(Wc[(size_t)k * 2048 + col]);
  }

  const int lane = tid & 63;
  const int g = tid >> 6;   // wave = gate
  const int lm = lane & 15;
  const int lq = lane >> 4;
  const int ko = lq * 8;

  // ---- one-time: lo-plane fragments -> VGPRs ----
  short8 w1l[6], w2l[16];
#pragma unroll
  for (int kt = 0; kt < 6; ++kt) {
    const int col = (g << 7) + jbase + lm;
#pragma unroll
    for (int e = 0; e < 8; ++e) {
      const int k = kt * 32 + ko + e;
      const float w = (k < 64) ? Ws[(size_t)(s * 64 + k) * 512 + col]
                               : Us[(size_t)(s * 128 + (k - 64)) * 512 + col];
      w1l[kt][e] = (short)f2b(w - b2f(f2b(w)));
    }
  }
#pragma unroll
  for (int kt = 0; kt < 16; ++kt) {
    const int col = (g << 9) + j0 + lm;
#pragma unroll
    for (int e = 0; e < 8; ++e) {
      const float w = Wc[(size_t)(kt * 32 + ko + e) * 2048 + col];
      w2l[kt][e] = (short)f2b(w - b2f(f2b(w)));
    }
  }
  const float biasv = biases[s * 512 + (g << 7) + jbase + lm];
  const float bcv = bcg[(g << 9) + j0 + lm];
  __syncthreads();

  const u16* w1r = &W1H[((g << 4) + lm) * 200];
  const u16* w2r = &W2H[((g << 4) + lm) * 520];
  const int brow = q * 16 + lm;
  const float* xrow = x + (size_t)brow * (512 * 256) + s * 64;
  const int hbase = brow * 512 + s * 128;
  const int arow_off = ((g << 6) + brow) * 512;

  // phase-3 mapping
  const int p3b = tid >> 4, p3j = tid & 15;
  const int p3ci = (q * 16 + p3b) * 512 + j0 + p3j;
  const size_t obase = (size_t)(q * 16 + p3b) * TSTEPS * 512 + j0 + p3j;
  float creg = 0.f, hprev = 0.f;

  // x prefetch registers for t=0
  float4 xa0, xb0, xa1, xb1;
  {
    const float* xp = xrow;
    xa0 = *(const float4*)(xp + ko);
    xb0 = *(const float4*)(xp + ko + 4);
    xa1 = *(const float4*)(xp + 32 + ko);
    xb1 = *(const float4*)(xp + 32 + ko + 4);
  }

  for (int t = 0; t < TSTEPS; ++t) {
    // ---- phase 1a: x-part of stage-1 (independent of h(t-1)) ----
    short8 xh[2], xl[2];
    split8v(xa0, xb0, xh[0], xl[0]);
    split8v(xa1, xb1, xh[1], xl[1]);
    floatx4 accA = {0.f, 0.f, 0.f, 0.f}, accB = {0.f, 0.f, 0.f, 0.f};
    floatx4 accC = {0.f, 0.f, 0.f, 0.f};
#pragma unroll
    for (int kt = 0; kt < 2; ++kt) {
      const short8 bh = ld8(w1r + kt * 32 + ko);
      accA = __builtin_amdgcn_mfma_f32_16x16x32_bf16(xh[kt], bh, accA, 0, 0, 0);
      accB = __builtin_amdgcn_mfma_f32_16x16x32_bf16(xl[kt], bh, accB, 0, 0, 0);
      accC = __builtin_amdgcn_mfma_f32_16x16x32_bf16(xh[kt], w1l[kt], accC, 0, 0, 0);
    }

    // ---- wait2: h(t-1) visibility (8-wide group; trivial at t=0) ----
    wait_flags(flags2, 7, (unsigned)t);

    // ---- phase 0b: h loads (L3), batched behind one drain ----
    short8 hh[4], hl[4];
#pragma unroll
    for (int kt = 0; kt < 4; ++kt) hh[kt] = lda_frag(&h_hi[hbase + kt * 32 + ko]);
#pragma unroll
    for (int kt = 0; kt < 4; ++kt) hl[kt] = lda_frag(&h_lo[hbase + kt * 32 + ko]);
    asm volatile("s_waitcnt vmcnt(0)" ::: "memory");
    __builtin_amdgcn_sched_barrier(0);

    // ---- phase 1b: h-part; activation; act stores (hi plane only) ----
    {
#pragma unroll
      for (int kt = 0; kt < 4; ++kt) {
        const short8 bh = ld8(w1r + 64 + kt * 32 + ko);
        accA = __builtin_amdgcn_mfma_f32_16x16x32_bf16(hh[kt], bh, accA, 0, 0, 0);
        accB = __builtin_amdgcn_mfma_f32_16x16x32_bf16(hl[kt], bh, accB, 0, 0, 0);
        accC = __builtin_amdgcn_mfma_f32_16x16x32_bf16(hh[kt], w1l[2 + kt], accC, 0, 0, 0);
      }
      const int pp = (t & 1) * ACT_PLANE;
#pragma unroll
      for (int r = 0; r < 4; ++r) {
        const int b = q * 16 + lq * 4 + r;
        const float pre = accA[r] + accB[r] + accC[r] + biasv;
        const float a = (g == 2) ? tanhf_fast(pre) : sigf(pre);
        sta16(&act_hi[pp + ((g << 6) + b) * 512 + j0 + lm], f2b(a));
      }
    }
    barrier_flags(flags1, 31, jt, (unsigned)(t + 1));

    // ---- phase 2: act loads (one drain); then out store + x prefetch
    //      (drain deferred to arrive2); connector GEMM ----
    short8 Ah[16];
    {
      const u16* ahp = act_hi + (t & 1) * ACT_PLANE + arow_off;
#pragma unroll
      for (int kt = 0; kt < 16; ++kt) Ah[kt] = lda_frag(ahp + kt * 32 + ko);
    }
    asm volatile("s_waitcnt vmcnt(0)" ::: "memory");
    __builtin_amdgcn_sched_barrier(0);
    if (t > 0) __builtin_nontemporal_store(hprev, &out[obase + (size_t)(t - 1) * 512]);
    {
      const float* xp = xrow + (size_t)(t < TSTEPS - 1 ? (t + 1) : t) * 256;
      xa0 = *(const float4*)(xp + ko);
      xb0 = *(const float4*)(xp + ko + 4);
      xa1 = *(const float4*)(xp + 32 + ko);
      xb1 = *(const float4*)(xp + 32 + ko + 4);
    }
    floatx4 a2a = {0.f, 0.f, 0.f, 0.f}, a2b = {0.f, 0.f, 0.f, 0.f};
    floatx4 a2c = {0.f, 0.f, 0.f, 0.f}, a2d = {0.f, 0.f, 0.f, 0.f};
#pragma unroll
    for (int kt = 0; kt < 16; kt += 2) {
      const int kb0 = kt * 32 + ko, kb1 = kb0 + 32;
      const short8 Bh0 = ld8(w2r + kb0), Bh1 = ld8(w2r + kb1);
      a2a = __builtin_amdgcn_mfma_f32_16x16x32_bf16(Ah[kt], Bh0, a2a, 0, 0, 0);
      a2b = __builtin_amdgcn_mfma_f32_16x16x32_bf16(Ah[kt], w2l[kt], a2b, 0, 0, 0);
      a2c = __builtin_amdgcn_mfma_f32_16x16x32_bf16(Ah[kt + 1], Bh1, a2c, 0, 0, 0);
      a2d = __builtin_amdgcn_mfma_f32_16x16x32_bf16(Ah[kt + 1], w2l[kt + 1], a2d, 0, 0, 0);
    }
#pragma unroll
    for (int r = 0; r < 4; ++r)
      gx[g][lq * 4 + r][lm] = (a2a[r] + a2c[r]) + (a2b[r] + a2d[r]) + bcv;
    __syncthreads();

    // ---- phase 3: elementwise update; h stores (sc1) ----
    {
      const float it = sigf(gx[0][p3b][p3j]);
      const float ft = sigf(gx[1][p3b][p3j]);
      const float gt = tanhf_fast(gx[2][p3b][p3j]);
      const float ot = sigf(gx[3][p3b][p3j]);
      const float cn = ft * creg + it * gt;
      creg = cn;
      const float h = ot * tanhf_fast(cn);
      hprev = h;
      if (t < TSTEPS - 1) {
        const u16 hh2 = f2b(h);
        sta16(&h_hi[p3ci], hh2);
        sta16(&h_lo[p3ci], f2b(h - b2f(hh2)));
      } else {
        __builtin_nontemporal_store(h, &out[obase + (size_t)t * 512]);
        __builtin_nontemporal_store(h, &out[16777216 + p3ci]);
        __builtin_nontemporal_store(cn, &out[16777216 + 32768 + p3ci]);
      }
    }
    // ---- arrive2: publish h(t); wait happens next iteration ----
    if (t < TSTEPS - 1) arrive_flags(flags2, jt & 7, (unsigned)(t + 1));
  }
}

extern "C" void kernel_launch(void* const* d_in, const int* in_sizes, int n_in,
                              void* d_out, int out_size, void* d_ws, size_t ws_size,
                              hipStream_t stream) {
  const float* x = (const float*)d_in[0];
  const float* Ws = (const float*)d_in[1];
  const float* Us = (const float*)d_in[2];
  const float* biases = (const float*)d_in[3];
  const float* Wc = (const float*)d_in[4];
  const float* bc = (const float*)d_in[5];

  char* ws = (char*)d_ws;
  unsigned* flagbase = (unsigned*)(ws + WS_FLAG1);
  u16* h_hi = (u16*)(ws + WS_H_HI);
  u16* h_lo = (u16*)(ws + WS_H_LO);
  u16* act_hi = (u16*)(ws + WS_ACT_HI);

  hipLaunchKernelGGL(init_ws_kernel, dim3(64), dim3(NT), 0, stream, (unsigned*)ws,
                     WS_ZERO_BYTES / 4);
  hipLaunchKernelGGL(slicelstm_kernel, dim3(NBLK), dim3(NT), 0, stream, x, Ws, Us,
                     biases, Wc, bc, (float*)d_out, act_hi, h_hi, h_lo, flagbase);
}

// Round 6
// 4442.479 us; speedup vs baseline: 1.5311x; 1.1028x over previous
//
#include <hip/hip_runtime.h>
#include <hip/hip_bf16.h>

// SliceLSTM persistent kernel for gfx950, round 10.
// Verified round-6/9 architecture: 128 blocks x 256 thr (4 batch quarters x
// 32 j-tiles, wave = gate), cross-block exchange via agent-scope (sc1/L3)
// relaxed atomics, flag barriers (32-wide acts, 8-wide h-group), watchdogs.
// Round-10 deltas (sync semantics untouched):
//  * h exchange is single bf16 plane (h_lo dropped, mirroring the measured-
//    safe act_lo drop; absmax sits on the 2^-10 output floor with 6x margin).
//    Halves h stores/loads, removes 4 MFMAs from the critical path.
//  * barrier1 split arrive/wait: hidden_seq store + x(t+1) prefetch are
//    issued in the arrive->wait gap (pinned by sched_barrier), so their HBM
//    latency hides under barrier skew instead of delaying arrive2's drain
//    (which gates next step's wait2).

typedef unsigned short u16;
typedef unsigned long long u64;
typedef __attribute__((ext_vector_type(8))) short short8;
typedef __attribute__((ext_vector_type(4))) float floatx4;

#define NT 256
#define NBLK 128
#define TSTEPS 512

// ---- workspace layout (bytes) ----
#define WS_FLAG1 0                        // 4 quarters x 32 u32 (256 B stride)
#define WS_FLAG2 1024                     // 16 groups x 8 u32 (64 B stride)
#define WS_H_HI 2048                      // 64 b x 512 j u16
#define WS_ZERO_BYTES (WS_H_HI + 65536)   // zeroed every call
#define WS_ACT_HI (WS_ZERO_BYTES)         // 2 planes x [4g][64b][512k] u16
#define ACT_PLANE 131072                  // elements per plane

__device__ __forceinline__ float b2f(u16 u) {
  unsigned v = ((unsigned)u) << 16;
  float f;
  __builtin_memcpy(&f, &v, 4);
  return f;
}
__device__ __forceinline__ u16 f2b(float f) {
  __hip_bfloat16 h = __float2bfloat16(f);  // RNE
  u16 u;
  __builtin_memcpy(&u, &h, 2);
  return u;
}
__device__ __forceinline__ float sigf(float x) { return 1.0f / (1.0f + __expf(-x)); }
__device__ __forceinline__ float tanhf_fast(float x) { return 2.0f * sigf(2.0f * x) - 1.0f; }
__device__ __forceinline__ short8 ld8(const u16* p) { return *(const short8*)p; }

// coherent 16B fragment load (sc1, straight from L3; relaxed -> batchable)
__device__ __forceinline__ short8 lda_frag(const u16* p) {
  union {
    u64 q[2];
    short8 s;
  } u;
  u.q[0] = __hip_atomic_load((const u64*)p, __ATOMIC_RELAXED, __HIP_MEMORY_SCOPE_AGENT);
  u.q[1] = __hip_atomic_load((const u64*)(p + 4), __ATOMIC_RELAXED, __HIP_MEMORY_SCOPE_AGENT);
  return u.s;
}
__device__ __forceinline__ void sta16(u16* p, u16 v) {
  __hip_atomic_store(p, v, __ATOMIC_RELAXED, __HIP_MEMORY_SCOPE_AGENT);
}

__device__ __forceinline__ void split8v(float4 a, float4 b, short8& hi, short8& lo) {
  float v[8] = {a.x, a.y, a.z, a.w, b.x, b.y, b.z, b.w};
#pragma unroll
  for (int i = 0; i < 8; ++i) {
    u16 h = f2b(v[i]);
    hi[i] = (short)h;
    lo[i] = (short)f2b(v[i] - b2f(h));
  }
}

// Wait-only half of a flag barrier: wave 0 polls, all threads gated after.
// Bounded spin: a deadlock becomes a fast wrong-answer, not a hang.
__device__ __forceinline__ void wait_flags(unsigned* flags, int nmask, unsigned target) {
  if (threadIdx.x < 64) {
    const int fi = threadIdx.x & nmask;
    int spins = 0;
    for (;;) {
      const unsigned v =
          __hip_atomic_load(&flags[fi], __ATOMIC_RELAXED, __HIP_MEMORY_SCOPE_AGENT);
      if (__ballot(v >= target) == ~0ULL) break;
      if (++spins > (1 << 24)) break;  // watchdog
      __builtin_amdgcn_s_sleep(1);
    }
  }
  __syncthreads();
}
// Arrive-only half: drain this block's stores, then publish the flag.
__device__ __forceinline__ void arrive_flags(unsigned* flags, int myidx, unsigned target) {
  asm volatile("s_waitcnt vmcnt(0)" ::: "memory");
  __syncthreads();
  if (threadIdx.x == 0)
    __hip_atomic_store(&flags[myidx], target, __ATOMIC_RELAXED, __HIP_MEMORY_SCOPE_AGENT);
}

__global__ void __launch_bounds__(NT) init_ws_kernel(unsigned* w, int n) {
  int i = blockIdx.x * blockDim.x + threadIdx.x;
  const int st = gridDim.x * blockDim.x;
  for (; i < n; i += st) w[i] = 0u;
}

__global__ void __launch_bounds__(NT, 1) slicelstm_kernel(
    const float* __restrict__ x, const float* __restrict__ Ws,
    const float* __restrict__ Us, const float* __restrict__ biases,
    const float* __restrict__ Wc, const float* __restrict__ bcg,
    float* __restrict__ out, u16* __restrict__ act_hi, u16* __restrict__ h_hi,
    unsigned* __restrict__ flagbase) {
  __shared__ __align__(16) u16 W1H[64 * 200];  // [row=g*16+jj][k 0..191] +8 pad
  __shared__ __align__(16) u16 W2H[64 * 520];  // [row=g*16+jj][k 0..511] +8 pad
  __shared__ float gx[4][16][17];              // gate exchange, +1 pad

  const int tid = threadIdx.x;
  const int blk = blockIdx.x;
  const int q = blk & 3;    // batch quarter
  const int jt = blk >> 2;  // j-tile 0..31
  const int j0 = jt * 16;
  const int s = j0 >> 7;    // slice 0..3
  const int jbase = j0 & 127;
  unsigned* flags1 = flagbase + q * 64;                        // 32 flags
  unsigned* flags2 = flagbase + 256 + (q * 4 + s) * 16;        // 8 flags

  // ---- one-time: split f32 weights, hi-planes -> LDS ----
  for (int i = tid; i < 64 * 192; i += NT) {
    const int r = i / 192, k = i % 192;
    const int col = (r >> 4) * 128 + jbase + (r & 15);
    const float w = (k < 64) ? Ws[(size_t)(s * 64 + k) * 512 + col]
                             : Us[(size_t)(s * 128 + (k - 64)) * 512 + col];
    W1H[r * 200 + k] = f2b(w);
  }
  for (int i = tid; i < 64 * 512; i += NT) {
    const int r = i >> 9, k = i & 511;
    const int col = (r >> 4) * 512 + j0 + (r & 15);
    W2H[r * 520 + k] = f2b(Wc[(size_t)k * 2048 + col]);
  }

  const int lane = tid & 63;
  const int g = tid >> 6;   // wave = gate
  const int lm = lane & 15;
  const int lq = lane >> 4;
  const int ko = lq * 8;

  // ---- one-time: lo-plane fragments -> VGPRs ----
  short8 w1l[6], w2l[16];
#pragma unroll
  for (int kt = 0; kt < 6; ++kt) {
    const int col = (g << 7) + jbase + lm;
#pragma unroll
    for (int e = 0; e < 8; ++e) {
      const int k = kt * 32 + ko + e;
      const float w = (k < 64) ? Ws[(size_t)(s * 64 + k) * 512 + col]
                               : Us[(size_t)(s * 128 + (k - 64)) * 512 + col];
      w1l[kt][e] = (short)f2b(w - b2f(f2b(w)));
    }
  }
#pragma unroll
  for (int kt = 0; kt < 16; ++kt) {
    const int col = (g << 9) + j0 + lm;
#pragma unroll
    for (int e = 0; e < 8; ++e) {
      const float w = Wc[(size_t)(kt * 32 + ko + e) * 2048 + col];
      w2l[kt][e] = (short)f2b(w - b2f(f2b(w)));
    }
  }
  const float biasv = biases[s * 512 + (g << 7) + jbase + lm];
  const float bcv = bcg[(g << 9) + j0 + lm];
  __syncthreads();

  const u16* w1r = &W1H[((g << 4) + lm) * 200];
  const u16* w2r = &W2H[((g << 4) + lm) * 520];
  const int brow = q * 16 + lm;
  const float* xrow = x + (size_t)brow * (512 * 256) + s * 64;
  const int hbase = brow * 512 + s * 128;
  const int arow_off = ((g << 6) + brow) * 512;

  // phase-3 mapping
  const int p3b = tid >> 4, p3j = tid & 15;
  const int p3ci = (q * 16 + p3b) * 512 + j0 + p3j;
  const size_t obase = (size_t)(q * 16 + p3b) * TSTEPS * 512 + j0 + p3j;
  float creg = 0.f, hprev = 0.f;

  // x prefetch registers for t=0
  float4 xa0, xb0, xa1, xb1;
  {
    const float* xp = xrow;
    xa0 = *(const float4*)(xp + ko);
    xb0 = *(const float4*)(xp + ko + 4);
    xa1 = *(const float4*)(xp + 32 + ko);
    xb1 = *(const float4*)(xp + 32 + ko + 4);
  }

  for (int t = 0; t < TSTEPS; ++t) {
    // ---- phase 1a: x-part of stage-1 (independent of h(t-1)) ----
    short8 xh[2], xl[2];
    split8v(xa0, xb0, xh[0], xl[0]);
    split8v(xa1, xb1, xh[1], xl[1]);
    floatx4 accA = {0.f, 0.f, 0.f, 0.f}, accB = {0.f, 0.f, 0.f, 0.f};
    floatx4 accC = {0.f, 0.f, 0.f, 0.f};
#pragma unroll
    for (int kt = 0; kt < 2; ++kt) {
      const short8 bh = ld8(w1r + kt * 32 + ko);
      accA = __builtin_amdgcn_mfma_f32_16x16x32_bf16(xh[kt], bh, accA, 0, 0, 0);
      accB = __builtin_amdgcn_mfma_f32_16x16x32_bf16(xl[kt], bh, accB, 0, 0, 0);
      accC = __builtin_amdgcn_mfma_f32_16x16x32_bf16(xh[kt], w1l[kt], accC, 0, 0, 0);
    }

    // ---- wait2: h(t-1) visibility (8-wide group; trivial at t=0) ----
    wait_flags(flags2, 7, (unsigned)t);

    // ---- phase 0b: h loads (L3, single plane), batched behind one drain ----
    short8 hh[4];
#pragma unroll
    for (int kt = 0; kt < 4; ++kt) hh[kt] = lda_frag(&h_hi[hbase + kt * 32 + ko]);
    asm volatile("s_waitcnt vmcnt(0)" ::: "memory");
    __builtin_amdgcn_sched_barrier(0);

    // ---- phase 1b: h-part; activation; act stores (hi plane only) ----
    {
#pragma unroll
      for (int kt = 0; kt < 4; ++kt) {
        const short8 bh = ld8(w1r + 64 + kt * 32 + ko);
        accA = __builtin_amdgcn_mfma_f32_16x16x32_bf16(hh[kt], bh, accA, 0, 0, 0);
        accC = __builtin_amdgcn_mfma_f32_16x16x32_bf16(hh[kt], w1l[2 + kt], accC, 0, 0, 0);
      }
      const int pp = (t & 1) * ACT_PLANE;
#pragma unroll
      for (int r = 0; r < 4; ++r) {
        const int b = q * 16 + lq * 4 + r;
        const float pre = accA[r] + accB[r] + accC[r] + biasv;
        const float a = (g == 2) ? tanhf_fast(pre) : sigf(pre);
        sta16(&act_hi[pp + ((g << 6) + b) * 512 + j0 + lm], f2b(a));
      }
    }
    // ---- arrive1; fill the skew gap with out store + x(t+1) prefetch ----
    arrive_flags(flags1, jt, (unsigned)(t + 1));
    if (t > 0) __builtin_nontemporal_store(hprev, &out[obase + (size_t)(t - 1) * 512]);
    {
      const float* xp = xrow + (size_t)(t < TSTEPS - 1 ? (t + 1) : t) * 256;
      xa0 = *(const float4*)(xp + ko);
      xb0 = *(const float4*)(xp + ko + 4);
      xa1 = *(const float4*)(xp + 32 + ko);
      xb1 = *(const float4*)(xp + 32 + ko + 4);
    }
    __builtin_amdgcn_sched_barrier(0);  // pin issue before the wait loop
    wait_flags(flags1, 31, (unsigned)(t + 1));

    // ---- phase 2: act loads (one drain); connector GEMM ----
    short8 Ah[16];
    {
      const u16* ahp = act_hi + (t & 1) * ACT_PLANE + arow_off;
#pragma unroll
      for (int kt = 0; kt < 16; ++kt) Ah[kt] = lda_frag(ahp + kt * 32 + ko);
    }
    asm volatile("s_waitcnt vmcnt(0)" ::: "memory");
    __builtin_amdgcn_sched_barrier(0);
    floatx4 a2a = {0.f, 0.f, 0.f, 0.f}, a2b = {0.f, 0.f, 0.f, 0.f};
    floatx4 a2c = {0.f, 0.f, 0.f, 0.f}, a2d = {0.f, 0.f, 0.f, 0.f};
#pragma unroll
    for (int kt = 0; kt < 16; kt += 2) {
      const int kb0 = kt * 32 + ko, kb1 = kb0 + 32;
      const short8 Bh0 = ld8(w2r + kb0), Bh1 = ld8(w2r + kb1);
      a2a = __builtin_amdgcn_mfma_f32_16x16x32_bf16(Ah[kt], Bh0, a2a, 0, 0, 0);
      a2b = __builtin_amdgcn_mfma_f32_16x16x32_bf16(Ah[kt], w2l[kt], a2b, 0, 0, 0);
      a2c = __builtin_amdgcn_mfma_f32_16x16x32_bf16(Ah[kt + 1], Bh1, a2c, 0, 0, 0);
      a2d = __builtin_amdgcn_mfma_f32_16x16x32_bf16(Ah[kt + 1], w2l[kt + 1], a2d, 0, 0, 0);
    }
#pragma unroll
    for (int r = 0; r < 4; ++r)
      gx[g][lq * 4 + r][lm] = (a2a[r] + a2c[r]) + (a2b[r] + a2d[r]) + bcv;
    __syncthreads();

    // ---- phase 3: elementwise update; h store (hi plane only) ----
    {
      const float it = sigf(gx[0][p3b][p3j]);
      const float ft = sigf(gx[1][p3b][p3j]);
      const float gt = tanhf_fast(gx[2][p3b][p3j]);
      const float ot = sigf(gx[3][p3b][p3j]);
      const float cn = ft * creg + it * gt;
      creg = cn;
      const float h = ot * tanhf_fast(cn);
      hprev = h;
      if (t < TSTEPS - 1) {
        sta16(&h_hi[p3ci], f2b(h));
      } else {
        __builtin_nontemporal_store(h, &out[obase + (size_t)t * 512]);
        __builtin_nontemporal_store(h, &out[16777216 + p3ci]);
        __builtin_nontemporal_store(cn, &out[16777216 + 32768 + p3ci]);
      }
    }
    // ---- arrive2: publish h(t); wait happens next iteration ----
    if (t < TSTEPS - 1) arrive_flags(flags2, jt & 7, (unsigned)(t + 1));
  }
}

extern "C" void kernel_launch(void* const* d_in, const int* in_sizes, int n_in,
                              void* d_out, int out_size, void* d_ws, size_t ws_size,
                              hipStream_t stream) {
  const float* x = (const float*)d_in[0];
  const float* Ws = (const float*)d_in[1];
  const float* Us = (const float*)d_in[2];
  const float* biases = (const float*)d_in[3];
  const float* Wc = (const float*)d_in[4];
  const float* bc = (const float*)d_in[5];

  char* ws = (char*)d_ws;
  unsigned* flagbase = (unsigned*)(ws + WS_FLAG1);
  u16* h_hi = (u16*)(ws + WS_H_HI);
  u16* act_hi = (u16*)(ws + WS_ACT_HI);

  hipLaunchKernelGGL(init_ws_kernel, dim3(64), dim3(NT), 0, stream, (unsigned*)ws,
                     WS_ZERO_BYTES / 4);
  hipLaunchKernelGGL(slicelstm_kernel, dim3(NBLK), dim3(NT), 0, stream, x, Ws, Us,
                     biases, Wc, bc, (float*)d_out, act_hi, h_hi, flagbase);
}